// Round 11
// baseline (90.458 us; speedup 1.0000x reference)
//
#include <hip/hip_runtime.h>
#include <hip/hip_bf16.h>
#include <math.h>

#define NCLS 151
#define NQ   100
#define NB   2
#define HW   16384   // 128*128
#define NCO  150     // classes after dropping class 0
#define OUTW 512
#define KPAD 128     // Q padded to 128
#define CPAD 160     // C padded to 160
#define CBLK 32      // classes per block (5 c-splits)
#define AROW 136     // s_a row stride in ushort (272 B)
#define BROW 72      // s_bt row stride in ushort (one 64-k half per row)
#define SROW 130     // s_seg row stride in float

using short8  = __attribute__((ext_vector_type(8))) short;
using f32x4   = __attribute__((ext_vector_type(4))) float;

static __device__ __forceinline__ ushort f2bf(float x) {
    union { float f; unsigned u; } v; v.f = x;
    unsigned r = v.u + 0x7fff + ((v.u >> 16) & 1);   // RNE
    return (ushort)(r >> 16);
}

// ---------------- Kernel 1: softmax -> transposed bf16 scores A[b][c][q] ----------------
__global__ __launch_bounds__(64) void softmax_k(const float* __restrict__ logits,
                                                ushort* __restrict__ scoresT) {
    int q = blockIdx.x & 127;
    int b = blockIdx.x >> 7;
    int lane = threadIdx.x;
    ushort* A = scoresT + (size_t)b * CPAD * KPAD;

    if (q >= NQ) {   // zero pad columns q in [100,128)
        A[lane * KPAD + q] = 0;
        A[(lane + 64) * KPAD + q] = 0;
        if (lane < 32) A[(lane + 128) * KPAD + q] = 0;
        return;
    }

    const float* in = logits + (size_t)(b * NQ + q) * NCLS;
    float v0 = in[lane];
    float v1 = in[lane + 64];
    float v2 = (lane < NCLS - 128) ? in[lane + 128] : -1e30f;

    float m = fmaxf(fmaxf(v0, v1), v2);
    #pragma unroll
    for (int o = 32; o; o >>= 1) m = fmaxf(m, __shfl_xor(m, o));

    float e0 = __expf(v0 - m);
    float e1 = __expf(v1 - m);
    float e2 = (lane < NCLS - 128) ? __expf(v2 - m) : 0.f;

    float s = e0 + e1 + e2;
    #pragma unroll
    for (int o = 32; o; o >>= 1) s += __shfl_xor(s, o);

    float inv = 1.f / s;
    if (lane >= 1) A[(lane - 1) * KPAD + q] = f2bf(e0 * inv);
    A[(lane + 63) * KPAD + q] = f2bf(e1 * inv);
    if (lane < 23)       A[(lane + 127) * KPAD + q] = f2bf(e2 * inv);
    else if (lane < 33)  A[(lane + 127) * KPAD + q] = 0;   // c-pad rows
}

// ---------------- Kernel 2: sigmoid + transpose masks -> BT[b][pix][128] bf16 ----------
// tile = 256 px x 32 q-slots. grid (HW/256, NB*4), 256 thr.
__global__ __launch_bounds__(256) void sigt_k(const float* __restrict__ masks,
                                              ushort* __restrict__ BT) {
    __shared__ unsigned s32[256][17];   // 17,408 B

    int bz = blockIdx.y;          // 0..7
    int b = bz >> 2, qh = bz & 3; // q-slot quarter
    int pix0 = blockIdx.x * 256;
    int tid = threadIdx.x;

    const float* mb = masks + (size_t)b * NQ * HW + pix0;
    #pragma unroll
    for (int j = 0; j < 16; ++j) {
        int q0 = qh * 32 + 2 * j, q1 = q0 + 1;
        unsigned lo = 0, hi = 0;
        if (q0 < NQ) lo = f2bf(1.f / (1.f + __expf(-__builtin_nontemporal_load(&mb[(size_t)q0 * HW + tid]))));
        if (q1 < NQ) hi = f2bf(1.f / (1.f + __expf(-__builtin_nontemporal_load(&mb[(size_t)q1 * HW + tid]))));
        s32[tid][j] = lo | (hi << 16);
    }
    __syncthreads();

    unsigned* out32 = (unsigned*)(BT + ((size_t)b * HW + pix0) * KPAD) + qh * 16;
    #pragma unroll
    for (int t = 0; t < 16; ++t) {
        int i = tid + t * 256;
        int p = i >> 4, d = i & 15;
        out32[p * 64 + d] = s32[p][d];
    }
}

// ---------------- Kernel 3: fused MFMA einsum + bilinear resize ----------------
// block 512 thr (8 waves); grid (128 row-pairs, NB*5 c-splits). 3 blocks/CU.
// LDS: s_a 8.7KB + union(s_bt-half 36.9KB, s_seg 33.3KB) = 45.6KB.
// Staging: vector b128 from pre-sigmoided BT. Emission: nontemporal stores.
__global__ __launch_bounds__(512, 6) void fused_k(const ushort* __restrict__ BT,
                                                  const ushort* __restrict__ scoresT,
                                                  float* __restrict__ out) {
    __shared__ __align__(16) ushort s_a[CBLK][AROW];          // 8,704 B
    __shared__ __align__(16) char uni[256 * BROW * 2];        // 36,864 B (union)
    ushort (*s_bt)[BROW] = (ushort(*)[BROW])uni;              // [256][72] (64-k half)
    float* s_seg = (float*)uni;                               // [2][CBLK][SROW]

    int r   = blockIdx.x;
    int b   = blockIdx.y / 5;
    int cs  = blockIdx.y % 5;
    int tid = threadIdx.x;
    int r1  = min(r + 1, 127);
    int wid = tid >> 6, lane = tid & 63;
    int pr = lane & 15, kg = lane >> 4;

    // ---- stage A slice (32 c x 128 k): one float4 chunk per thread ----
    {
        const float4* asrc = (const float4*)(scoresT + (size_t)(b * CPAD + cs * CBLK) * KPAD);
        float4 av = asrc[tid];
        int c = tid >> 4, kc = tid & 15;
        *(float4*)&s_a[c][kc * 8] = av;
    }

    f32x4 acc[2][2];
    #pragma unroll
    for (int ct = 0; ct < 2; ++ct)
        #pragma unroll
        for (int nt = 0; nt < 2; ++nt) acc[ct][nt] = (f32x4){0.f, 0.f, 0.f, 0.f};

    const ushort* bbase = BT + (size_t)b * HW * KPAD;

    #pragma unroll
    for (int kc2 = 0; kc2 < 2; ++kc2) {
        // ---- stage one 64-k half of B: 4 coalesced float4 loads per thread ----
        #pragma unroll
        for (int j = 0; j < 4; ++j) {
            int i = tid + j * 512;           // 2048 chunks (256 px x 8)
            int p = i >> 3, kc = i & 7;
            int gpix = ((p < 128) ? r : r1) * 128 + (p & 127);
            float4 v = *(const float4*)(bbase + (size_t)gpix * KPAD + kc2 * 64 + kc * 8);
            *(float4*)&s_bt[p][kc * 8] = v;
        }
        __syncthreads();

        // ---- MFMA on this half: 2 k-steps x 2 c-tiles x 2 n-tiles ----
        #pragma unroll
        for (int ks = 0; ks < 2; ++ks) {
            short8 b0 = *(const short8*)&s_bt[wid * 32 + pr][ks * 32 + kg * 8];
            short8 b1 = *(const short8*)&s_bt[wid * 32 + 16 + pr][ks * 32 + kg * 8];
            #pragma unroll
            for (int ct = 0; ct < 2; ++ct) {
                short8 af = *(const short8*)&s_a[ct * 16 + pr][kc2 * 64 + ks * 32 + kg * 8];
                acc[ct][0] = __builtin_amdgcn_mfma_f32_16x16x32_bf16(af, b0, acc[ct][0], 0, 0, 0);
                acc[ct][1] = __builtin_amdgcn_mfma_f32_16x16x32_bf16(af, b1, acc[ct][1], 0, 0, 0);
            }
        }
        __syncthreads();   // half reads complete before overwrite / union reuse
    }

    // ---- acc -> s_seg (union: s_bt dead) (D layout: row = kg*4+j, col = pr) ----
    #pragma unroll
    for (int ct = 0; ct < 2; ++ct)
        #pragma unroll
        for (int nt = 0; nt < 2; ++nt) {
            int p = wid * 32 + nt * 16 + pr;
            int rs = p >> 7, px = p & 127;
            #pragma unroll
            for (int j = 0; j < 4; ++j) {
                int c = ct * 16 + kg * 4 + j;
                s_seg[(rs * CBLK + c) * SROW + px] = acc[ct][nt][j];
            }
        }
    __syncthreads();

    // ---- emission: w-lerps once per (c,k), nontemporal float4 stores ----
    int cbase = cs * CBLK;
    for (int it = tid; it < CBLK * 128; it += 512) {
        int k = it & 127;
        int c = it >> 7;
        int cg = cbase + c;
        if (cg >= NCO) break;                 // wave-uniform
        int km = max(k - 1, 0), kp = min(k + 1, 127);
        const float* s0 = &s_seg[c * SROW];
        const float* s1 = &s_seg[(CBLK + c) * SROW];
        float a0 = s0[km], a1 = s0[k], a2 = s0[kp];
        float b0 = s1[km], b1 = s1[k], b2 = s1[kp];

        float t0 = a0 + 0.625f * (a1 - a0);
        float t1 = a0 + 0.875f * (a1 - a0);
        float t2 = a1 + 0.125f * (a2 - a1);
        float t3 = a1 + 0.375f * (a2 - a1);
        float u0 = b0 + 0.625f * (b1 - b0);
        float u1 = b0 + 0.875f * (b1 - b0);
        float u2 = b1 + 0.125f * (b2 - b1);
        float u3 = b1 + 0.375f * (b2 - b1);

        float* op = out + (size_t)(b * NCO + cg) * (OUTW * OUTW) + 4 * k;

        if (r == 0) {                         // rows 0,1: clamped -> pure w-lerp
            f32x4 o = {t0, t1, t2, t3};
            __builtin_nontemporal_store(o, (f32x4*)(op));
            __builtin_nontemporal_store(o, (f32x4*)(op + OUTW));
        }
        int nr = (r == 127) ? 2 : 4;
        #pragma unroll
        for (int ri = 0; ri < 4; ++ri) {
            if (ri >= nr) break;              // wave-uniform
            float fh = 0.125f + 0.25f * (float)ri;
            int h = 4 * r + 2 + ri;
            f32x4 o;
            o.x = t0 + fh * (u0 - t0);
            o.y = t1 + fh * (u1 - t1);
            o.z = t2 + fh * (u2 - t2);
            o.w = t3 + fh * (u3 - t3);
            __builtin_nontemporal_store(o, (f32x4*)(op + (size_t)h * OUTW));
        }
    }
}

extern "C" void kernel_launch(void* const* d_in, const int* in_sizes, int n_in,
                              void* d_out, int out_size, void* d_ws, size_t ws_size,
                              hipStream_t stream) {
    const float* logits = (const float*)d_in[0];
    const float* masks  = (const float*)d_in[1];
    float* out = (float*)d_out;

    ushort* scoresT = (ushort*)d_ws;                      // 81,920 B
    ushort* BT      = (ushort*)((char*)d_ws + (1 << 17)); // 8,388,608 B

    softmax_k<<<dim3(NB * 128), dim3(64), 0, stream>>>(logits, scoresT);
    sigt_k<<<dim3(HW / 256, NB * 4), dim3(256), 0, stream>>>(masks, BT);
    fused_k<<<dim3(128, NB * 5), dim3(512), 0, stream>>>(BT, scoresT, out);
}

// Round 12
// 73.301 us; speedup vs baseline: 1.2341x; 1.2341x over previous
//
#include <hip/hip_runtime.h>
#include <hip/hip_bf16.h>
#include <math.h>

#define NCLS 151
#define NQ   100
#define NB   2
#define HW   16384   // 128*128
#define NCO  150     // classes after dropping class 0
#define OUTW 512
#define KPAD 128     // Q padded to 128
#define CPAD 160     // C padded to 160
#define CBLK 32      // classes per block (5 c-splits)
#define AROW 136     // s_a row stride in ushort (272 B)
#define BROW 72      // s_bt row stride in ushort (one 64-k half per row)
#define SROW 130     // s_seg row stride in float

using short8  = __attribute__((ext_vector_type(8))) short;
using short4v = __attribute__((ext_vector_type(4))) short;
using f32x4   = __attribute__((ext_vector_type(4))) float;

static __device__ __forceinline__ ushort f2bf(float x) {
    union { float f; unsigned u; } v; v.f = x;
    unsigned r = v.u + 0x7fff + ((v.u >> 16) & 1);   // RNE
    return (ushort)(r >> 16);
}

// ---------------- Kernel 1: softmax -> transposed bf16 scores A[b][c][q] ----------------
__global__ __launch_bounds__(64) void softmax_k(const float* __restrict__ logits,
                                                ushort* __restrict__ scoresT) {
    int q = blockIdx.x & 127;
    int b = blockIdx.x >> 7;
    int lane = threadIdx.x;
    ushort* A = scoresT + (size_t)b * CPAD * KPAD;

    if (q >= NQ) {   // zero pad columns q in [100,128)
        A[lane * KPAD + q] = 0;
        A[(lane + 64) * KPAD + q] = 0;
        if (lane < 32) A[(lane + 128) * KPAD + q] = 0;
        return;
    }

    const float* in = logits + (size_t)(b * NQ + q) * NCLS;
    float v0 = in[lane];
    float v1 = in[lane + 64];
    float v2 = (lane < NCLS - 128) ? in[lane + 128] : -1e30f;

    float m = fmaxf(fmaxf(v0, v1), v2);
    #pragma unroll
    for (int o = 32; o; o >>= 1) m = fmaxf(m, __shfl_xor(m, o));

    float e0 = __expf(v0 - m);
    float e1 = __expf(v1 - m);
    float e2 = (lane < NCLS - 128) ? __expf(v2 - m) : 0.f;

    float s = e0 + e1 + e2;
    #pragma unroll
    for (int o = 32; o; o >>= 1) s += __shfl_xor(s, o);

    float inv = 1.f / s;
    if (lane >= 1) A[(lane - 1) * KPAD + q] = f2bf(e0 * inv);
    A[(lane + 63) * KPAD + q] = f2bf(e1 * inv);
    if (lane < 23)       A[(lane + 127) * KPAD + q] = f2bf(e2 * inv);
    else if (lane < 33)  A[(lane + 127) * KPAD + q] = 0;   // c-pad rows
}

// ---------------- Kernel 2: fused sigmoid + MFMA einsum + bilinear resize --------------
// block 512 thr (8 waves); grid (128 row-pairs, NB*5 c-splits).
// LDS: s_a 8.7KB + union(s_bt-half 36.9KB, s_seg 33.3KB) = 45.6KB -> 3 blocks/CU.
// kc2 half order staggered by r-parity to decorrelate co-resident blocks' phases.
// Output stores NONTEMPORAL (keep masks/scores in L2).
__global__ __launch_bounds__(512, 6) void fused_k(const float* __restrict__ masks,
                                                  const ushort* __restrict__ scoresT,
                                                  float* __restrict__ out) {
    __shared__ __align__(16) ushort s_a[CBLK][AROW];          // 8,704 B
    __shared__ __align__(16) char uni[256 * BROW * 2];        // 36,864 B (union)
    ushort (*s_bt)[BROW] = (ushort(*)[BROW])uni;              // [256][72] (64-k half)
    float* s_seg = (float*)uni;                               // [2][CBLK][SROW]

    int r   = blockIdx.x;
    int b   = blockIdx.y / 5;
    int cs  = blockIdx.y % 5;
    int tid = threadIdx.x;
    int r1  = min(r + 1, 127);
    int wid = tid >> 6, lane = tid & 63;
    int pr = lane & 15, kg = lane >> 4;

    // ---- stage A slice (32 c x 128 k): one float4 chunk per thread ----
    {
        const float4* asrc = (const float4*)(scoresT + (size_t)(b * CPAD + cs * CBLK) * KPAD);
        float4 av = asrc[tid];
        int c = tid >> 4, kc = tid & 15;
        *(float4*)&s_a[c][kc * 8] = av;
    }

    f32x4 acc[2][2];
    #pragma unroll
    for (int ct = 0; ct < 2; ++ct)
        #pragma unroll
        for (int nt = 0; nt < 2; ++nt) acc[ct][nt] = (f32x4){0.f, 0.f, 0.f, 0.f};

    const float* mb = masks + (size_t)b * NQ * HW;
    int par = r & 1;   // phase stagger

    #pragma unroll
    for (int kk = 0; kk < 2; ++kk) {
        int kc2 = kk ^ par;
        // ---- stage one 64-k half of B^T with in-kernel sigmoid ----
        #pragma unroll
        for (int i0 = 0; i0 < 4096; i0 += 512) {
            int i = i0 + tid;
            int p = i & 255, kk4 = i >> 8;               // kk4 uniform per wave
            int gpix = ((p < 128) ? r : r1) * 128 + (p & 127);
            short4v sv;
            #pragma unroll
            for (int e = 0; e < 4; ++e) {
                int gk = kc2 * 64 + kk4 * 4 + e;
                float s = 0.f;
                if (gk < NQ) {
                    float x = mb[(size_t)gk * HW + gpix];
                    s = 1.f / (1.f + __expf(-x));
                }
                sv[e] = (short)f2bf(s);
            }
            *(short4v*)&s_bt[p][kk4 * 4] = sv;
        }
        __syncthreads();

        // ---- MFMA on this half: 2 k-steps x 2 c-tiles x 2 n-tiles ----
        #pragma unroll
        for (int ks = 0; ks < 2; ++ks) {
            short8 b0 = *(const short8*)&s_bt[wid * 32 + pr][ks * 32 + kg * 8];
            short8 b1 = *(const short8*)&s_bt[wid * 32 + 16 + pr][ks * 32 + kg * 8];
            #pragma unroll
            for (int ct = 0; ct < 2; ++ct) {
                short8 af = *(const short8*)&s_a[ct * 16 + pr][kc2 * 64 + ks * 32 + kg * 8];
                acc[ct][0] = __builtin_amdgcn_mfma_f32_16x16x32_bf16(af, b0, acc[ct][0], 0, 0, 0);
                acc[ct][1] = __builtin_amdgcn_mfma_f32_16x16x32_bf16(af, b1, acc[ct][1], 0, 0, 0);
            }
        }
        __syncthreads();   // half reads complete before overwrite / union reuse
    }

    // ---- acc -> s_seg (union: s_bt dead) (D layout: row = kg*4+j, col = pr) ----
    #pragma unroll
    for (int ct = 0; ct < 2; ++ct)
        #pragma unroll
        for (int nt = 0; nt < 2; ++nt) {
            int p = wid * 32 + nt * 16 + pr;
            int rs = p >> 7, px = p & 127;
            #pragma unroll
            for (int j = 0; j < 4; ++j) {
                int c = ct * 16 + kg * 4 + j;
                s_seg[(rs * CBLK + c) * SROW + px] = acc[ct][nt][j];
            }
        }
    __syncthreads();

    // ---- emission: w-lerps once per (c,k), nontemporal float4 stores ----
    int cbase = cs * CBLK;
    for (int it = tid; it < CBLK * 128; it += 512) {
        int k = it & 127;
        int c = it >> 7;
        int cg = cbase + c;
        if (cg >= NCO) break;                 // wave-uniform
        int km = max(k - 1, 0), kp = min(k + 1, 127);
        const float* s0 = &s_seg[c * SROW];
        const float* s1 = &s_seg[(CBLK + c) * SROW];
        float a0 = s0[km], a1 = s0[k], a2 = s0[kp];
        float b0 = s1[km], b1 = s1[k], b2 = s1[kp];

        float t0 = a0 + 0.625f * (a1 - a0);
        float t1 = a0 + 0.875f * (a1 - a0);
        float t2 = a1 + 0.125f * (a2 - a1);
        float t3 = a1 + 0.375f * (a2 - a1);
        float u0 = b0 + 0.625f * (b1 - b0);
        float u1 = b0 + 0.875f * (b1 - b0);
        float u2 = b1 + 0.125f * (b2 - b1);
        float u3 = b1 + 0.375f * (b2 - b1);

        float* op = out + (size_t)(b * NCO + cg) * (OUTW * OUTW) + 4 * k;

        if (r == 0) {                         // rows 0,1: clamped -> pure w-lerp
            f32x4 o = {t0, t1, t2, t3};
            __builtin_nontemporal_store(o, (f32x4*)(op));
            __builtin_nontemporal_store(o, (f32x4*)(op + OUTW));
        }
        int nr = (r == 127) ? 2 : 4;
        #pragma unroll
        for (int ri = 0; ri < 4; ++ri) {
            if (ri >= nr) break;              // wave-uniform
            float fh = 0.125f + 0.25f * (float)ri;
            int h = 4 * r + 2 + ri;
            f32x4 o;
            o.x = t0 + fh * (u0 - t0);
            o.y = t1 + fh * (u1 - t1);
            o.z = t2 + fh * (u2 - t2);
            o.w = t3 + fh * (u3 - t3);
            __builtin_nontemporal_store(o, (f32x4*)(op + (size_t)h * OUTW));
        }
    }
}

extern "C" void kernel_launch(void* const* d_in, const int* in_sizes, int n_in,
                              void* d_out, int out_size, void* d_ws, size_t ws_size,
                              hipStream_t stream) {
    const float* logits = (const float*)d_in[0];
    const float* masks  = (const float*)d_in[1];
    float* out = (float*)d_out;

    ushort* scoresT = (ushort*)d_ws;   // 81,920 B

    softmax_k<<<dim3(NB * 128), dim3(64), 0, stream>>>(logits, scoresT);
    fused_k<<<dim3(128, NB * 5), dim3(512), 0, stream>>>(masks, scoresT, out);
}

// Round 13
// 72.085 us; speedup vs baseline: 1.2549x; 1.0169x over previous
//
#include <hip/hip_runtime.h>
#include <hip/hip_bf16.h>
#include <math.h>

#define NCLS 151
#define NQ   100
#define NB   2
#define HW   16384   // 128*128
#define NCO  150     // classes after dropping class 0
#define OUTW 512
#define KPAD 128     // Q padded to 128
#define CPAD 160     // C padded to 160
#define CBLK 32      // classes per c-split (5 splits, looped in-kernel)
#define AROW 136     // s_a row stride in ushort (272 B, 16B-aligned, 2-way-free banks)
#define BROW 136     // s_bt row stride in ushort
#define SROW 130     // s_seg row stride in float

using short8  = __attribute__((ext_vector_type(8))) short;
using short4v = __attribute__((ext_vector_type(4))) short;
using f32x4   = __attribute__((ext_vector_type(4))) float;

static __device__ __forceinline__ ushort f2bf(float x) {
    union { float f; unsigned u; } v; v.f = x;
    unsigned r = v.u + 0x7fff + ((v.u >> 16) & 1);   // RNE
    return (ushort)(r >> 16);
}

// ---------------- Kernel 1: softmax -> transposed bf16 scores A[b][c][q] ----------------
__global__ __launch_bounds__(64) void softmax_k(const float* __restrict__ logits,
                                                ushort* __restrict__ scoresT) {
    int q = blockIdx.x & 127;
    int b = blockIdx.x >> 7;
    int lane = threadIdx.x;
    ushort* A = scoresT + (size_t)b * CPAD * KPAD;

    if (q >= NQ) {   // zero pad columns q in [100,128)
        A[lane * KPAD + q] = 0;
        A[(lane + 64) * KPAD + q] = 0;
        if (lane < 32) A[(lane + 128) * KPAD + q] = 0;
        return;
    }

    const float* in = logits + (size_t)(b * NQ + q) * NCLS;
    float v0 = in[lane];
    float v1 = in[lane + 64];
    float v2 = (lane < NCLS - 128) ? in[lane + 128] : -1e30f;

    float m = fmaxf(fmaxf(v0, v1), v2);
    #pragma unroll
    for (int o = 32; o; o >>= 1) m = fmaxf(m, __shfl_xor(m, o));

    float e0 = __expf(v0 - m);
    float e1 = __expf(v1 - m);
    float e2 = (lane < NCLS - 128) ? __expf(v2 - m) : 0.f;

    float s = e0 + e1 + e2;
    #pragma unroll
    for (int o = 32; o; o >>= 1) s += __shfl_xor(s, o);

    float inv = 1.f / s;
    if (lane >= 1) A[(lane - 1) * KPAD + q] = f2bf(e0 * inv);
    A[(lane + 63) * KPAD + q] = f2bf(e1 * inv);
    if (lane < 23)       A[(lane + 127) * KPAD + q] = f2bf(e2 * inv);
    else if (lane < 33)  A[(lane + 127) * KPAD + q] = 0;   // c-pad rows
}

// ---------------- Kernel 2: mega-block fused sigmoid + MFMA + resize ----------------
// ONE block per CU: grid (128 r-pairs, 2 batches) = 256 blocks, 512 thr (8 waves).
// Stage A (all 160 classes) + B^T (256 px x 128 k, sigmoided) ONCE,
// then loop 5 c-splits: MFMA -> s_seg -> emit (nontemporal stores).
// LDS = 43.5 + 69.6 + 33.3 = 146.4 KB.
__global__ __launch_bounds__(512, 2) void fused_k(const float* __restrict__ masks,
                                                  const ushort* __restrict__ scoresT,
                                                  float* __restrict__ out) {
    __shared__ __align__(16) ushort s_a[CPAD][AROW];     // 43,520 B
    __shared__ __align__(16) ushort s_bt[256][BROW];     // 69,632 B
    __shared__ float s_seg[2][CBLK][SROW];               // 33,280 B

    int r   = blockIdx.x;
    int b   = blockIdx.y;
    int tid = threadIdx.x;
    int r1  = min(r + 1, 127);
    int wid = tid >> 6, lane = tid & 63;
    int pr = lane & 15, kg = lane >> 4;

    // ---- stage A: 160 c x 128 k bf16 = 2560 float4 chunks, 5 per thread ----
    {
        const float4* asrc = (const float4*)(scoresT + (size_t)b * CPAD * KPAD);
        #pragma unroll
        for (int j = 0; j < 5; ++j) {
            int i = tid + j * 512;
            float4 v = asrc[i];
            int c = i >> 4, kc = i & 15;
            *(float4*)&s_a[c][kc * 8] = v;
        }
    }

    // ---- stage B^T with in-kernel sigmoid: 256 px x 128 k ----
    {
        const float* mb = masks + (size_t)b * NQ * HW;
        #pragma unroll
        for (int i0 = 0; i0 < 8192; i0 += 512) {
            int i = i0 + tid;
            int p = i & 255, kk4 = i >> 8;               // kk4 wave-uniform
            int gpix = ((p < 128) ? r : r1) * 128 + (p & 127);
            short4v sv;
            #pragma unroll
            for (int e = 0; e < 4; ++e) {
                int gk = kk4 * 4 + e;
                float s = 0.f;
                if (gk < NQ) {
                    float x = mb[(size_t)gk * HW + gpix];
                    s = 1.f / (1.f + __expf(-x));
                }
                sv[e] = (short)f2bf(s);
            }
            *(short4v*)&s_bt[p][kk4 * 4] = sv;
        }
    }
    __syncthreads();

    // ---- loop over 5 c-splits: MFMA -> s_seg -> emission ----
    for (int cs = 0; cs < 5; ++cs) {
        f32x4 acc[2][2];
        #pragma unroll
        for (int ct = 0; ct < 2; ++ct)
            #pragma unroll
            for (int nt = 0; nt < 2; ++nt) acc[ct][nt] = (f32x4){0.f, 0.f, 0.f, 0.f};

        #pragma unroll
        for (int ks = 0; ks < 4; ++ks) {
            short8 b0 = *(const short8*)&s_bt[wid * 32 + pr][ks * 32 + kg * 8];
            short8 b1 = *(const short8*)&s_bt[wid * 32 + 16 + pr][ks * 32 + kg * 8];
            #pragma unroll
            for (int ct = 0; ct < 2; ++ct) {
                short8 af = *(const short8*)&s_a[cs * CBLK + ct * 16 + pr][ks * 32 + kg * 8];
                acc[ct][0] = __builtin_amdgcn_mfma_f32_16x16x32_bf16(af, b0, acc[ct][0], 0, 0, 0);
                acc[ct][1] = __builtin_amdgcn_mfma_f32_16x16x32_bf16(af, b1, acc[ct][1], 0, 0, 0);
            }
        }

        __syncthreads();   // previous cs emission reads of s_seg complete

        // ---- acc -> s_seg (D layout: row = kg*4+j, col = pr) ----
        #pragma unroll
        for (int ct = 0; ct < 2; ++ct)
            #pragma unroll
            for (int nt = 0; nt < 2; ++nt) {
                int p = wid * 32 + nt * 16 + pr;
                int rs = p >> 7, px = p & 127;
                #pragma unroll
                for (int j = 0; j < 4; ++j) {
                    int c = ct * 16 + kg * 4 + j;
                    s_seg[rs][c][px] = acc[ct][nt][j];
                }
            }
        __syncthreads();

        // ---- emission: w-lerps once per (c,k), nontemporal float4 stores ----
        int cbase = cs * CBLK;
        for (int it = tid; it < CBLK * 128; it += 512) {
            int k = it & 127;
            int c = it >> 7;                  // wave-uniform
            int cg = cbase + c;
            if (cg >= NCO) break;             // wave-uniform (only cs=4 trims)
            int km = max(k - 1, 0), kp = min(k + 1, 127);
            const float* s0 = s_seg[0][c];
            const float* s1 = s_seg[1][c];
            float a0 = s0[km], a1 = s0[k], a2 = s0[kp];
            float b0 = s1[km], b1 = s1[k], b2 = s1[kp];

            float t0 = a0 + 0.625f * (a1 - a0);
            float t1 = a0 + 0.875f * (a1 - a0);
            float t2 = a1 + 0.125f * (a2 - a1);
            float t3 = a1 + 0.375f * (a2 - a1);
            float u0 = b0 + 0.625f * (b1 - b0);
            float u1 = b0 + 0.875f * (b1 - b0);
            float u2 = b1 + 0.125f * (b2 - b1);
            float u3 = b1 + 0.375f * (b2 - b1);

            float* op = out + (size_t)(b * NCO + cg) * (OUTW * OUTW) + 4 * k;

            if (r == 0) {                     // rows 0,1: clamped -> pure w-lerp
                f32x4 o = {t0, t1, t2, t3};
                __builtin_nontemporal_store(o, (f32x4*)(op));
                __builtin_nontemporal_store(o, (f32x4*)(op + OUTW));
            }
            int nr = (r == 127) ? 2 : 4;
            #pragma unroll
            for (int ri = 0; ri < 4; ++ri) {
                if (ri >= nr) break;          // wave-uniform
                float fh = 0.125f + 0.25f * (float)ri;
                int h = 4 * r + 2 + ri;
                f32x4 o;
                o.x = t0 + fh * (u0 - t0);
                o.y = t1 + fh * (u1 - t1);
                o.z = t2 + fh * (u2 - t2);
                o.w = t3 + fh * (u3 - t3);
                __builtin_nontemporal_store(o, (f32x4*)(op + (size_t)h * OUTW));
            }
        }
    }
}

extern "C" void kernel_launch(void* const* d_in, const int* in_sizes, int n_in,
                              void* d_out, int out_size, void* d_ws, size_t ws_size,
                              hipStream_t stream) {
    const float* logits = (const float*)d_in[0];
    const float* masks  = (const float*)d_in[1];
    float* out = (float*)d_out;

    ushort* scoresT = (ushort*)d_ws;   // 81,920 B

    softmax_k<<<dim3(NB * 128), dim3(64), 0, stream>>>(logits, scoresT);
    fused_k<<<dim3(128, NB), dim3(512), 0, stream>>>(masks, scoresT, out);
}

// Round 14
// 68.955 us; speedup vs baseline: 1.3118x; 1.0454x over previous
//
#include <hip/hip_runtime.h>
#include <hip/hip_bf16.h>
#include <math.h>

#define NCLS 151
#define NQ   100
#define NB   2
#define HW   16384   // 128*128
#define NCO  150     // classes after dropping class 0
#define OUTW 512
#define KPAD 128     // Q padded to 128
#define CPAD 160     // C padded to 160
#define CBLK 32      // classes per c-split (5 splits, looped in-kernel)
#define AROW 136     // s_a row stride in ushort
#define BROW 136     // s_bt row stride in ushort
#define SROW 130     // s_seg row stride in float

using short8  = __attribute__((ext_vector_type(8))) short;
using short4v = __attribute__((ext_vector_type(4))) short;
using f32x4   = __attribute__((ext_vector_type(4))) float;

static __device__ __forceinline__ ushort f2bf(float x) {
    union { float f; unsigned u; } v; v.f = x;
    unsigned r = v.u + 0x7fff + ((v.u >> 16) & 1);   // RNE
    return (ushort)(r >> 16);
}

// ---------------- Kernel 1: softmax -> transposed bf16 scores A[b][c][q] ----------------
__global__ __launch_bounds__(64) void softmax_k(const float* __restrict__ logits,
                                                ushort* __restrict__ scoresT) {
    int q = blockIdx.x & 127;
    int b = blockIdx.x >> 7;
    int lane = threadIdx.x;
    ushort* A = scoresT + (size_t)b * CPAD * KPAD;

    if (q >= NQ) {   // zero pad columns q in [100,128)
        A[lane * KPAD + q] = 0;
        A[(lane + 64) * KPAD + q] = 0;
        if (lane < 32) A[(lane + 128) * KPAD + q] = 0;
        return;
    }

    const float* in = logits + (size_t)(b * NQ + q) * NCLS;
    float v0 = in[lane];
    float v1 = in[lane + 64];
    float v2 = (lane < NCLS - 128) ? in[lane + 128] : -1e30f;

    float m = fmaxf(fmaxf(v0, v1), v2);
    #pragma unroll
    for (int o = 32; o; o >>= 1) m = fmaxf(m, __shfl_xor(m, o));

    float e0 = __expf(v0 - m);
    float e1 = __expf(v1 - m);
    float e2 = (lane < NCLS - 128) ? __expf(v2 - m) : 0.f;

    float s = e0 + e1 + e2;
    #pragma unroll
    for (int o = 32; o; o >>= 1) s += __shfl_xor(s, o);

    float inv = 1.f / s;
    if (lane >= 1) A[(lane - 1) * KPAD + q] = f2bf(e0 * inv);
    A[(lane + 63) * KPAD + q] = f2bf(e1 * inv);
    if (lane < 23)       A[(lane + 127) * KPAD + q] = f2bf(e2 * inv);
    else if (lane < 33)  A[(lane + 127) * KPAD + q] = 0;   // c-pad rows
}

// ---------------- Kernel 2: mega-block fused sigmoid + MFMA + resize ----------------
// ONE block per CU: grid (128 r-pairs, 2 batches) = 256 blocks, 512 thr (8 waves).
// Identical to R13 except output stores are NORMAL (through L2), not nontemporal.
__global__ __launch_bounds__(512, 2) void fused_k(const float* __restrict__ masks,
                                                  const ushort* __restrict__ scoresT,
                                                  float* __restrict__ out) {
    __shared__ __align__(16) ushort s_a[CPAD][AROW];     // 43,520 B
    __shared__ __align__(16) ushort s_bt[256][BROW];     // 69,632 B
    __shared__ float s_seg[2][CBLK][SROW];               // 33,280 B

    int r   = blockIdx.x;
    int b   = blockIdx.y;
    int tid = threadIdx.x;
    int r1  = min(r + 1, 127);
    int wid = tid >> 6, lane = tid & 63;
    int pr = lane & 15, kg = lane >> 4;

    // ---- stage A: 160 c x 128 k bf16 = 2560 float4 chunks, 5 per thread ----
    {
        const float4* asrc = (const float4*)(scoresT + (size_t)b * CPAD * KPAD);
        #pragma unroll
        for (int j = 0; j < 5; ++j) {
            int i = tid + j * 512;
            float4 v = asrc[i];
            int c = i >> 4, kc = i & 15;
            *(float4*)&s_a[c][kc * 8] = v;
        }
    }

    // ---- stage B^T with in-kernel sigmoid: 256 px x 128 k ----
    {
        const float* mb = masks + (size_t)b * NQ * HW;
        #pragma unroll
        for (int i0 = 0; i0 < 8192; i0 += 512) {
            int i = i0 + tid;
            int p = i & 255, kk4 = i >> 8;               // kk4 wave-uniform
            int gpix = ((p < 128) ? r : r1) * 128 + (p & 127);
            short4v sv;
            #pragma unroll
            for (int e = 0; e < 4; ++e) {
                int gk = kk4 * 4 + e;
                float s = 0.f;
                if (gk < NQ) {
                    float x = mb[(size_t)gk * HW + gpix];
                    s = 1.f / (1.f + __expf(-x));
                }
                sv[e] = (short)f2bf(s);
            }
            *(short4v*)&s_bt[p][kk4 * 4] = sv;
        }
    }
    __syncthreads();

    // ---- loop over 5 c-splits: MFMA -> s_seg -> emission ----
    for (int cs = 0; cs < 5; ++cs) {
        f32x4 acc[2][2];
        #pragma unroll
        for (int ct = 0; ct < 2; ++ct)
            #pragma unroll
            for (int nt = 0; nt < 2; ++nt) acc[ct][nt] = (f32x4){0.f, 0.f, 0.f, 0.f};

        #pragma unroll
        for (int ks = 0; ks < 4; ++ks) {
            short8 b0 = *(const short8*)&s_bt[wid * 32 + pr][ks * 32 + kg * 8];
            short8 b1 = *(const short8*)&s_bt[wid * 32 + 16 + pr][ks * 32 + kg * 8];
            #pragma unroll
            for (int ct = 0; ct < 2; ++ct) {
                short8 af = *(const short8*)&s_a[cs * CBLK + ct * 16 + pr][ks * 32 + kg * 8];
                acc[ct][0] = __builtin_amdgcn_mfma_f32_16x16x32_bf16(af, b0, acc[ct][0], 0, 0, 0);
                acc[ct][1] = __builtin_amdgcn_mfma_f32_16x16x32_bf16(af, b1, acc[ct][1], 0, 0, 0);
            }
        }

        __syncthreads();   // previous cs emission reads of s_seg complete

        // ---- acc -> s_seg (D layout: row = kg*4+j, col = pr) ----
        #pragma unroll
        for (int ct = 0; ct < 2; ++ct)
            #pragma unroll
            for (int nt = 0; nt < 2; ++nt) {
                int p = wid * 32 + nt * 16 + pr;
                int rs = p >> 7, px = p & 127;
                #pragma unroll
                for (int j = 0; j < 4; ++j) {
                    int c = ct * 16 + kg * 4 + j;
                    s_seg[rs][c][px] = acc[ct][nt][j];
                }
            }
        __syncthreads();

        // ---- emission: w-lerps once per (c,k), normal float4 stores ----
        int cbase = cs * CBLK;
        for (int it = tid; it < CBLK * 128; it += 512) {
            int k = it & 127;
            int c = it >> 7;                  // wave-uniform
            int cg = cbase + c;
            if (cg >= NCO) break;             // wave-uniform (only cs=4 trims)
            int km = max(k - 1, 0), kp = min(k + 1, 127);
            const float* s0 = s_seg[0][c];
            const float* s1 = s_seg[1][c];
            float a0 = s0[km], a1 = s0[k], a2 = s0[kp];
            float b0 = s1[km], b1 = s1[k], b2 = s1[kp];

            float t0 = a0 + 0.625f * (a1 - a0);
            float t1 = a0 + 0.875f * (a1 - a0);
            float t2 = a1 + 0.125f * (a2 - a1);
            float t3 = a1 + 0.375f * (a2 - a1);
            float u0 = b0 + 0.625f * (b1 - b0);
            float u1 = b0 + 0.875f * (b1 - b0);
            float u2 = b1 + 0.125f * (b2 - b1);
            float u3 = b1 + 0.375f * (b2 - b1);

            float* op = out + (size_t)(b * NCO + cg) * (OUTW * OUTW) + 4 * k;

            if (r == 0) {                     // rows 0,1: clamped -> pure w-lerp
                f32x4 o = {t0, t1, t2, t3};
                *(f32x4*)(op) = o;
                *(f32x4*)(op + OUTW) = o;
            }
            int nr = (r == 127) ? 2 : 4;
            #pragma unroll
            for (int ri = 0; ri < 4; ++ri) {
                if (ri >= nr) break;          // wave-uniform
                float fh = 0.125f + 0.25f * (float)ri;
                int h = 4 * r + 2 + ri;
                f32x4 o;
                o.x = t0 + fh * (u0 - t0);
                o.y = t1 + fh * (u1 - t1);
                o.z = t2 + fh * (u2 - t2);
                o.w = t3 + fh * (u3 - t3);
                *(f32x4*)(op + (size_t)h * OUTW) = o;
            }
        }
    }
}

extern "C" void kernel_launch(void* const* d_in, const int* in_sizes, int n_in,
                              void* d_out, int out_size, void* d_ws, size_t ws_size,
                              hipStream_t stream) {
    const float* logits = (const float*)d_in[0];
    const float* masks  = (const float*)d_in[1];
    float* out = (float*)d_out;

    ushort* scoresT = (ushort*)d_ws;   // 81,920 B

    softmax_k<<<dim3(NB * 128), dim3(64), 0, stream>>>(logits, scoresT);
    fused_k<<<dim3(128, NB), dim3(512), 0, stream>>>(masks, scoresT, out);
}